// Round 1
// baseline (270.066 us; speedup 1.0000x reference)
//
#include <hip/hip_runtime.h>

#define D 128

typedef unsigned short u16;
typedef unsigned int   u32;
typedef __attribute__((ext_vector_type(8))) short bf16x8;
typedef __attribute__((ext_vector_type(4))) float f32x4;

__device__ __forceinline__ u16 f32_to_bf16(float f) {
    unsigned u = __float_as_uint(f);
    unsigned rounding = 0x7fffu + ((u >> 16) & 1u);   // round-to-nearest-even
    return (u16)((u + rounding) >> 16);
}

__device__ __forceinline__ float bf16_to_f32(u16 s) {
    return __uint_as_float(((unsigned)s) << 16);
}

// -------------------------------------------------------------------------
// Kernel 0: Wt[n][k] = bf16(W[k][n]).  16384 elements, 64 blocks.
// -------------------------------------------------------------------------
__global__ __launch_bounds__(256) void prep_kernel(
    const float* __restrict__ W, u16* __restrict__ Wt)
{
    int idx = blockIdx.x * 256 + threadIdx.x;   // idx = n*128 + k
    int n = idx >> 7;
    int k = idx & 127;
    Wt[idx] = f32_to_bf16(W[k * 128 + n]);
}

// -------------------------------------------------------------------------
// Kernel 1: support = bf16(x @ W + b) via MFMA 16x16x32 bf16.  (unchanged)
// -------------------------------------------------------------------------
__global__ __launch_bounds__(256) void gemm_mfma_kernel(
    const float* __restrict__ x, const u16* __restrict__ Wt,
    const float* __restrict__ b, u16* __restrict__ sup, int N)
{
    const int lane = threadIdx.x & 63;
    const int wave = threadIdx.x >> 6;
    const int col  = lane & 15;
    const int quad = lane >> 4;
    const int row0 = blockIdx.x * 64 + wave * 16;
    const int m    = row0 + col;
    const bool mvalid = (m < N);

    f32x4 acc[8];
    #pragma unroll
    for (int nt = 0; nt < 8; ++nt) {
        float bias = b[nt * 16 + col];
        acc[nt][0] = bias; acc[nt][1] = bias;
        acc[nt][2] = bias; acc[nt][3] = bias;
    }

    const float* xrow = x + (size_t)m * D;

    #pragma unroll
    for (int ks = 0; ks < 4; ++ks) {
        const int k0 = ks * 32 + quad * 8;

        float af[8];
        if (mvalid) {
            float4 v0 = *(const float4*)(xrow + k0);
            float4 v1 = *(const float4*)(xrow + k0 + 4);
            af[0] = v0.x; af[1] = v0.y; af[2] = v0.z; af[3] = v0.w;
            af[4] = v1.x; af[5] = v1.y; af[6] = v1.z; af[7] = v1.w;
        } else {
            #pragma unroll
            for (int j = 0; j < 8; ++j) af[j] = 0.f;
        }

        bf16x8 ahi, alo;
        #pragma unroll
        for (int j = 0; j < 8; ++j) {
            u16 h = f32_to_bf16(af[j]);
            float r = af[j] - bf16_to_f32(h);
            ahi[j] = (short)h;
            alo[j] = (short)f32_to_bf16(r);
        }

        #pragma unroll
        for (int nt = 0; nt < 8; ++nt) {
            bf16x8 bfrag = *(const bf16x8*)(Wt + (size_t)(nt * 16 + col) * D + k0);
            acc[nt] = __builtin_amdgcn_mfma_f32_16x16x32_bf16(alo, bfrag, acc[nt], 0, 0, 0);
            acc[nt] = __builtin_amdgcn_mfma_f32_16x16x32_bf16(ahi, bfrag, acc[nt], 0, 0, 0);
        }
    }

    #pragma unroll
    for (int reg = 0; reg < 4; ++reg) {
        int r = row0 + quad * 4 + reg;
        if (r < N) {
            #pragma unroll
            for (int nt = 0; nt < 8; ++nt) {
                sup[(size_t)r * D + nt * 16 + col] = f32_to_bf16(acc[nt][reg]);
            }
        }
    }
}

// -------------------------------------------------------------------------
// Kernel 2: row_ptr from sorted edge_dst. rp[n] = lower_bound(edge_dst, n).
// -------------------------------------------------------------------------
__global__ __launch_bounds__(256) void rowptr_kernel(
    const int* __restrict__ edst, int* __restrict__ rp, int E, int N)
{
    int e = blockIdx.x * 256 + threadIdx.x;
    if (e >= E) return;
    int d = edst[e];
    int prev = (e == 0) ? -1 : edst[e - 1];
    for (int n = prev + 1; n <= d; ++n) rp[n] = e;
    if (e == E - 1) {
        for (int n = d + 1; n <= N; ++n) rp[n] = E;
    }
}

// -------------------------------------------------------------------------
// Kernel 3 (REWRITTEN): SpMM, one wave per node, full 128-feature row.
// Lane l owns features {2l, 2l+1} (one dword of 2 bf16).
//  - src index and weight are broadcast to SGPRs via readlane (constant
//    index after unroll), so the row pointer sup + s*128 is wave-uniform:
//    per-edge addressing goes to the SALU pipe and the gather is emitted
//    as global_load_dword v, v_laneoff, s[rowbase] -- one fully-coalesced
//    256 B row per instruction.
//  - No cross-lane epilogue reduce: each lane accumulates its own two
//    features and writes one float2.
//  - esrc/ew read exactly once per edge (was twice with the half split).
//  - 8-deep unrolled gather batches for memory-level parallelism; tail
//    edges (t >= cnt) have sv=0, wv=0 -> harmless gather of row 0 * 0.
// -------------------------------------------------------------------------
__global__ __launch_bounds__(256) void spmm_kernel(
    const u16* __restrict__ sup, const float* __restrict__ ew,
    const int* __restrict__ esrc, const int* __restrict__ rp,
    float* __restrict__ out, int N)
{
    const int wave = threadIdx.x >> 6;
    const int lane = threadIdx.x & 63;
    const int node = blockIdx.x * 4 + wave;
    if (node >= N) return;

    const int start = __builtin_amdgcn_readfirstlane(rp[node]);
    const int end   = __builtin_amdgcn_readfirstlane(rp[node + 1]);

    float acc0 = 0.f;
    float acc1 = 0.f;

    for (int base = start; base < end; base += 64) {
        const int cnt = min(64, end - base);
        const int mi  = base + lane;
        int sv = 0;
        int wv = 0;
        if (mi < end) {
            sv = esrc[mi];
            wv = __float_as_int(ew[mi]);
        }

        for (int i0 = 0; i0 < cnt; i0 += 8) {
            u32 u[8];
            float wf[8];
            #pragma unroll
            for (int t = 0; t < 8; ++t) {
                int s  = __builtin_amdgcn_readlane(sv, i0 + t);   // SGPR
                int wb = __builtin_amdgcn_readlane(wv, i0 + t);   // SGPR
                const u32* prow = (const u32*)(sup + ((size_t)(u32)s << 7));
                u[t]  = prow[lane];            // uniform base + lane offset
                wf[t] = __int_as_float(wb);    // stays scalar
            }
            #pragma unroll
            for (int t = 0; t < 8; ++t) {
                acc0 = fmaf(wf[t], __uint_as_float(u[t] << 16),         acc0);
                acc1 = fmaf(wf[t], __uint_as_float(u[t] & 0xffff0000u), acc1);
            }
        }
    }

    float2 o = make_float2(acc0, acc1);
    *(float2*)(out + (size_t)node * D + lane * 2) = o;
}

extern "C" void kernel_launch(void* const* d_in, const int* in_sizes, int n_in,
                              void* d_out, int out_size, void* d_ws, size_t ws_size,
                              hipStream_t stream) {
    const float* x    = (const float*)d_in[0];
    const float* W    = (const float*)d_in[1];
    const float* b    = (const float*)d_in[2];
    const float* ew   = (const float*)d_in[3];
    const int*   esrc = (const int*)d_in[4];
    const int*   edst = (const int*)d_in[5];
    float* out = (float*)d_out;

    const int N = in_sizes[0] / D;
    const int E = in_sizes[3];

    u16* sup = (u16*)d_ws;                                        // N*128 bf16
    int* rp  = (int*)((char*)d_ws + (size_t)N * D * sizeof(u16)); // N+1 ints
    u16* Wt  = (u16*)((char*)rp + ((size_t)N + 16) * sizeof(int));// 128*128 bf16

    hipLaunchKernelGGL(prep_kernel, dim3(64), dim3(256), 0, stream, W, Wt);
    hipLaunchKernelGGL(gemm_mfma_kernel, dim3((N + 63) / 64), dim3(256), 0, stream,
                       x, Wt, b, sup, N);
    hipLaunchKernelGGL(rowptr_kernel, dim3((E + 255) / 256), dim3(256), 0, stream,
                       edst, rp, E, N);

    hipLaunchKernelGGL(spmm_kernel, dim3((N + 3) / 4), dim3(256), 0, stream,
                       sup, ew, esrc, rp, out, N);
}